// Round 1
// baseline (1992.820 us; speedup 1.0000x reference)
//
#include <hip/hip_runtime.h>

#define NSRC 50000
#define NDST 50000
#define NE   1600000
#define DD   64
#define NEG  0.2f
#define EB   128   // edges per block in k_edge

// ---------------- workspace layout (bytes) ----------------
#define OFF_FS      ((size_t)0)
#define OFF_FD      (OFF_FS     + (size_t)NSRC*DD*4)          // 12.8 MB
#define OFF_LOGITS  (OFF_FD     + (size_t)NDST*DD*4)          // +12.8 MB
#define OFF_WLA     (OFF_LOGITS + (size_t)NE*4)               // +6.4 MB
#define OFF_CNT     (OFF_WLA    + 512)
#define OFF_CUR     (OFF_CNT    + (size_t)NDST*4 + 256)
#define OFF_ROWOFF  (OFF_CUR    + (size_t)NDST*4 + 256)
#define OFF_BSUM    (OFF_ROWOFF + (size_t)(NDST+1)*4 + 252)
#define OFF_BBASE   (OFF_BSUM   + 1024)
#define OFF_PERM    (OFF_BBASE  + 1024)                        // +6.4 MB  => ~39.7 MB total

// ---------------- K1: node projections + cnt zero + wla precompute ----------------
__global__ __launch_bounds__(256) void k_nodeproj(
    const float* __restrict__ feat_src, const float* __restrict__ feat_dst,
    const float* __restrict__ W_src, const float* __restrict__ b_src,
    const float* __restrict__ W_dst, const float* __restrict__ b_dst,
    const float* __restrict__ W_el, const float* __restrict__ b_el,
    const float* __restrict__ attn,
    float* __restrict__ fs, float* __restrict__ fd,
    float* __restrict__ wla, int* __restrict__ cnt)
{
    __shared__ float Ws[2][DD*DD];   // 32 KB
    int t = threadIdx.x, b = blockIdx.x;
    {
        const float4* wa = (const float4*)W_src;
        const float4* wb = (const float4*)W_dst;
        float4* sa = (float4*)&Ws[0][0];
        float4* sb = (float4*)&Ws[1][0];
        for (int i = t; i < DD*DD/4; i += 256) { sa[i] = wa[i]; sb[i] = wb[i]; }
    }
    int gid = b*256 + t;
    if (gid < NDST) cnt[gid] = 0;
    if (b == 0) {
        if (t < DD) {                       // wla[k] = sum_j W_el[k][j]*attn[j]
            float s = 0.f;
            for (int j = 0; j < DD; j++) s += W_el[t*DD+j]*attn[j];
            wla[t] = s;
        } else if (t == DD) {               // bla = b_el . attn
            float s = 0.f;
            for (int j = 0; j < DD; j++) s += b_el[j]*attn[j];
            wla[DD] = s;
        }
    }
    __syncthreads();
    int row = gid;
    if (row >= NSRC + NDST) return;
    int which = (row < NSRC) ? 0 : 1;
    int r = which ? (row - NSRC) : row;
    const float* feat = which ? feat_dst : feat_src;
    const float* bias = which ? b_dst : b_src;
    float* outp = which ? (fd + (size_t)r*DD) : (fs + (size_t)r*DD);
    const float* W = Ws[which];

    float acc[DD];
#pragma unroll
    for (int j = 0; j < DD; j++) acc[j] = 0.f;

    const float4* frow4 = (const float4*)(feat + (size_t)r*DD);
    for (int k4 = 0; k4 < DD/4; k4++) {
        float4 x4 = frow4[k4];
#pragma unroll
        for (int c = 0; c < 4; c++) {
            float xk = (c==0)?x4.x:(c==1)?x4.y:(c==2)?x4.z:x4.w;
            const float4* wr = (const float4*)&W[(k4*4+c)*DD];
#pragma unroll
            for (int jq = 0; jq < DD/4; jq++) {
                float4 w = wr[jq];
                acc[jq*4+0] += xk*w.x; acc[jq*4+1] += xk*w.y;
                acc[jq*4+2] += xk*w.z; acc[jq*4+3] += xk*w.w;
            }
        }
    }
#pragma unroll
    for (int jq = 0; jq < DD/4; jq++) {
        float4 o;
        o.x = acc[jq*4+0] + bias[jq*4+0];
        o.y = acc[jq*4+1] + bias[jq*4+1];
        o.z = acc[jq*4+2] + bias[jq*4+2];
        o.w = acc[jq*4+3] + bias[jq*4+3];
        ((float4*)outp)[jq] = o;
    }
}

// ---------------- K2: histogram of dst ----------------
__global__ void k_hist(const int* __restrict__ dst_idx, int* __restrict__ cnt) {
    int e = blockIdx.x*256 + threadIdx.x;
    if (e < NE) atomicAdd(&cnt[dst_idx[e]], 1);
}

// ---------------- scan (3 phases) ----------------
__global__ __launch_bounds__(1024) void k_scan_a(const int* __restrict__ cnt,
                                                 int* __restrict__ row_off,
                                                 int* __restrict__ bsum) {
    __shared__ int sm[1024];
    int t = threadIdx.x, b = blockIdx.x;
    int i = b*1024 + t;
    int v = (i < NDST) ? cnt[i] : 0;
    sm[t] = v;
    __syncthreads();
    for (int o = 1; o < 1024; o <<= 1) {
        int add = (t >= o) ? sm[t-o] : 0;
        __syncthreads();
        sm[t] += add;
        __syncthreads();
    }
    if (i < NDST) row_off[i+1] = sm[t];
    if (t == 1023) bsum[b] = sm[t];
}

__global__ void k_scan_b(const int* __restrict__ bsum, int* __restrict__ bbase,
                         int* __restrict__ row_off, int nb) {
    if (threadIdx.x == 0 && blockIdx.x == 0) {
        int run = 0;
        for (int b = 0; b < nb; b++) { bbase[b] = run; run += bsum[b]; }
        row_off[0] = 0;
    }
}

__global__ __launch_bounds__(1024) void k_scan_c(const int* __restrict__ cnt,
                                                 const int* __restrict__ bbase,
                                                 int* __restrict__ row_off,
                                                 int* __restrict__ cur) {
    int t = threadIdx.x, b = blockIdx.x;
    int i = b*1024 + t;
    if (i < NDST) {
        int v = row_off[i+1] + bbase[b];
        row_off[i+1] = v;
        cur[i] = v - cnt[i];       // exclusive prefix = bucket start
    }
}

// ---------------- scatter into CSR ----------------
__global__ void k_scatter(const int* __restrict__ dst_idx, int* __restrict__ cur,
                          int* __restrict__ perm) {
    int e = blockIdx.x*256 + threadIdx.x;
    if (e < NE) {
        int p = atomicAdd(&cur[dst_idx[e]], 1);
        perm[p] = e;
    }
}

// ---------------- K_EDGE: fused per-edge pipeline -> logits ----------------
// x = e_feat@W_e + b_e + fs[src]; x = lrelu(x)@W_m1+b_m1; ... @W_m3+b_m3;
// y = lrelu(x + fd[dst]); logit = y . wla + bla
__global__ __launch_bounds__(EB) void k_edge(
    const float* __restrict__ e_feat,
    const float* __restrict__ W_e,  const float* __restrict__ b_e,
    const float* __restrict__ W_m1, const float* __restrict__ b_m1,
    const float* __restrict__ W_m2, const float* __restrict__ b_m2,
    const float* __restrict__ W_m3, const float* __restrict__ b_m3,
    const int* __restrict__ src_idx, const int* __restrict__ dst_idx,
    const float* __restrict__ fs, const float* __restrict__ fd,
    const float* __restrict__ wla,
    float* __restrict__ logits)
{
    __shared__ float Wl[DD*DD];        // 16 KB, reloaded per stage
    __shared__ float xs[DD][EB+2];     // transposed x tile, stride 130 -> conflict-free
    __shared__ float bsh[4*DD + DD + 4];

    int t = threadIdx.x;
    int e = blockIdx.x*EB + t;
    int src = src_idx[e];
    int dst = dst_idx[e];

    if (t < DD) {
        bsh[t]        = b_e[t];
        bsh[DD+t]     = b_m1[t];
        bsh[2*DD+t]   = b_m2[t];
        bsh[3*DD+t]   = b_m3[t];
        bsh[4*DD+t]   = wla[t];
    }
    if (t == DD) bsh[5*DD] = wla[DD];  // bla

    // stage e_feat tile into LDS (coalesced global read, scattered LDS write)
    {
        const float4* ef4 = (const float4*)(e_feat + (size_t)blockIdx.x*EB*DD);
#pragma unroll
        for (int it = 0; it < (EB*DD/4)/EB; it++) {   // 16 iters
            int f = t + EB*it;
            float4 v = ef4[f];
            int i  = f >> 4;        // edge in tile
            int j4 = f & 15;        // float4 within row
            xs[j4*4+0][i] = v.x; xs[j4*4+1][i] = v.y;
            xs[j4*4+2][i] = v.z; xs[j4*4+3][i] = v.w;
        }
    }

    float acc[DD];
#pragma unroll
    for (int s = 0; s < 4; s++) {
        const float* Wg = (s==0) ? W_e : (s==1) ? W_m1 : (s==2) ? W_m2 : W_m3;
        __syncthreads();   // prior stage's W reads (and tile staging) complete
        {
            const float4* wg = (const float4*)Wg;
            float4* wl4 = (float4*)Wl;
#pragma unroll
            for (int i = 0; i < (DD*DD/4)/EB; i++)   // 8 iters
                wl4[t + EB*i] = wg[t + EB*i];
        }
        __syncthreads();

#pragma unroll
        for (int j = 0; j < DD; j++) acc[j] = 0.f;

        for (int k = 0; k < DD; k++) {
            float xk = xs[k][t];
            if (s > 0) xk = fmaxf(xk, NEG*xk);   // leaky relu on stage input
            const float4* wr = (const float4*)&Wl[k*DD];
#pragma unroll
            for (int jq = 0; jq < DD/4; jq++) {
                float4 w = wr[jq];
                acc[jq*4+0] += xk*w.x; acc[jq*4+1] += xk*w.y;
                acc[jq*4+2] += xk*w.z; acc[jq*4+3] += xk*w.w;
            }
        }

        if (s == 0) {
            const float4* fsr = (const float4*)(fs + (size_t)src*DD);
#pragma unroll
            for (int jq = 0; jq < DD/4; jq++) {
                float4 v = fsr[jq];
                acc[jq*4+0] += v.x + bsh[jq*4+0];
                acc[jq*4+1] += v.y + bsh[jq*4+1];
                acc[jq*4+2] += v.z + bsh[jq*4+2];
                acc[jq*4+3] += v.w + bsh[jq*4+3];
            }
        } else if (s < 3) {
#pragma unroll
            for (int j = 0; j < DD; j++) acc[j] += bsh[s*DD+j];
        } else {
            const float4* fdr = (const float4*)(fd + (size_t)dst*DD);
            float lg = bsh[5*DD];
#pragma unroll
            for (int jq = 0; jq < DD/4; jq++) {
                float4 v = fdr[jq];
#pragma unroll
                for (int c = 0; c < 4; c++) {
                    float vv = (c==0)?v.x:(c==1)?v.y:(c==2)?v.z:v.w;
                    float y = acc[jq*4+c] + bsh[3*DD+jq*4+c] + vv;
                    y = fmaxf(y, NEG*y);
                    lg += y * bsh[4*DD+jq*4+c];
                }
            }
            logits[e] = lg;
        }

        if (s < 3) {
#pragma unroll
            for (int k = 0; k < DD; k++) xs[k][t] = acc[k];  // private column, no barrier
        }
    }
}

// ---------------- K_AGG: per-dst softmax + weighted aggregation ----------------
__global__ __launch_bounds__(256) void k_agg(
    const int* __restrict__ row_off, const int* __restrict__ perm,
    const float* __restrict__ logits, const int* __restrict__ src_idx,
    const float* __restrict__ fs, float* __restrict__ out)
{
    int w = threadIdx.x >> 6, lane = threadIdx.x & 63;
    int d = blockIdx.x*4 + w;
    if (d >= NDST) return;
    int off = row_off[d], end = row_off[d+1];
    int deg = end - off;

    float m = -1e30f;
    for (int i = lane; i < deg; i += 64)
        m = fmaxf(m, logits[perm[off+i]]);
#pragma unroll
    for (int s = 32; s >= 1; s >>= 1)
        m = fmaxf(m, __shfl_xor(m, s, 64));

    float ssum = 0.f, acc = 0.f;
    for (int i = 0; i < deg; i++) {
        int e = perm[off+i];
        float p = __expf(logits[e] - m);     // all lanes identical (broadcast loads)
        ssum += p;
        acc += p * fs[(size_t)src_idx[e]*DD + lane];
    }
    out[(size_t)d*DD + lane] = (deg > 0) ? (acc / ssum) : 0.f;
}

// ---------------- launch ----------------
extern "C" void kernel_launch(void* const* d_in, const int* in_sizes, int n_in,
                              void* d_out, int out_size, void* d_ws, size_t ws_size,
                              hipStream_t stream)
{
    const float* feat_src = (const float*)d_in[0];
    const float* feat_dst = (const float*)d_in[1];
    const float* e_feat   = (const float*)d_in[2];
    const float* W_src = (const float*)d_in[3];
    const float* b_src = (const float*)d_in[4];
    const float* W_dst = (const float*)d_in[5];
    const float* b_dst = (const float*)d_in[6];
    const float* W_e   = (const float*)d_in[7];
    const float* b_e   = (const float*)d_in[8];
    const float* W_m1  = (const float*)d_in[9];
    const float* b_m1  = (const float*)d_in[10];
    const float* W_m2  = (const float*)d_in[11];
    const float* b_m2  = (const float*)d_in[12];
    const float* W_m3  = (const float*)d_in[13];
    const float* b_m3  = (const float*)d_in[14];
    const float* W_el  = (const float*)d_in[15];
    const float* b_el  = (const float*)d_in[16];
    const float* attn  = (const float*)d_in[17];
    const int* src_idx = (const int*)d_in[18];
    const int* dst_idx = (const int*)d_in[19];
    float* out = (float*)d_out;

    char* ws = (char*)d_ws;
    float* fs      = (float*)(ws + OFF_FS);
    float* fd      = (float*)(ws + OFF_FD);
    float* logits  = (float*)(ws + OFF_LOGITS);
    float* wla     = (float*)(ws + OFF_WLA);
    int*   cnt     = (int*)  (ws + OFF_CNT);
    int*   cur     = (int*)  (ws + OFF_CUR);
    int*   row_off = (int*)  (ws + OFF_ROWOFF);
    int*   bsum    = (int*)  (ws + OFF_BSUM);
    int*   bbase   = (int*)  (ws + OFF_BBASE);
    int*   perm    = (int*)  (ws + OFF_PERM);

    const int NB_NODE = (NSRC + NDST + 255) / 256;   // 391
    const int NB_E256 = (NE + 255) / 256;            // 6250
    const int NB_SCAN = (NDST + 1023) / 1024;        // 49

    k_nodeproj<<<NB_NODE, 256, 0, stream>>>(feat_src, feat_dst, W_src, b_src,
                                            W_dst, b_dst, W_el, b_el, attn,
                                            fs, fd, wla, cnt);
    k_hist<<<NB_E256, 256, 0, stream>>>(dst_idx, cnt);
    k_scan_a<<<NB_SCAN, 1024, 0, stream>>>(cnt, row_off, bsum);
    k_scan_b<<<1, 64, 0, stream>>>(bsum, bbase, row_off, NB_SCAN);
    k_scan_c<<<NB_SCAN, 1024, 0, stream>>>(cnt, bbase, row_off, cur);
    k_scatter<<<NB_E256, 256, 0, stream>>>(dst_idx, cur, perm);
    k_edge<<<NE/EB, EB, 0, stream>>>(e_feat, W_e, b_e, W_m1, b_m1, W_m2, b_m2,
                                     W_m3, b_m3, src_idx, dst_idx, fs, fd, wla,
                                     logits);
    k_agg<<<(NDST + 3) / 4, 256, 0, stream>>>(row_off, perm, logits, src_idx, fs, out);
}